// Round 3
// baseline (333.969 us; speedup 1.0000x reference)
//
#include <hip/hip_runtime.h>
#include <hip/hip_bf16.h>

// LSTM_80960133529703: B=16384, T=24, F=7, H=8, L=4; dense 192->1024->2048->4.
// R3: (a) GEMM tiles 256x128 (wave tile 128x64, 8x4 acc) -> MFMA:LDS clk ratio
//     0.61->0.81, 2x fewer barriers/FLOP, halved atomics; (b) LSTM activations
//     via v_exp2/v_rcp builtins (kills v_div_* sequences); (c) FUSE3 epilogue
//     Cs stride 152 ushorts (conflict-free column dot), two row-passes.
// ws: Y bf16 [16384,192] @0 | H1 bf16 [16384,1024] @6291456
//     W1b @39845888 | W2b @40239104 | W3b @44433408

typedef __attribute__((ext_vector_type(4))) float f32x4;
typedef __attribute__((ext_vector_type(8))) short bf16x8;

__device__ __forceinline__ ushort f2bf(float f) {
    union { float f; uint u; } v; v.f = f;
    uint u = v.u;
    return (ushort)((u + 0x7fffu + ((u >> 16) & 1u)) >> 16);   // RNE
}
__device__ __forceinline__ float bf2f(ushort h) {
    union { uint u; float f; } v; v.u = ((uint)h) << 16;
    return v.f;
}
// fast: sigm = rcp(1+2^(-x*log2e)); tanh = 2*rcp(1+2^(-2x*log2e)) - 1
__device__ __forceinline__ float sigm(float x) {
    return __builtin_amdgcn_rcpf(1.0f + __builtin_amdgcn_exp2f(x * -1.442695040888963f));
}
__device__ __forceinline__ float tanh_(float x) {
    return 2.0f * __builtin_amdgcn_rcpf(1.0f + __builtin_amdgcn_exp2f(x * -2.885390081777927f)) - 1.0f;
}

// async global->LDS, 16 B/lane; LDS dest = wave-uniform base + lane*16.
typedef const __attribute__((address_space(1))) unsigned int ga_u32;
typedef __attribute__((address_space(3))) unsigned int lds_u32;
__device__ __forceinline__ void g2l16(const void* g, void* l) {
    __builtin_amdgcn_global_load_lds((ga_u32*)(unsigned long long)g,
                                     (lds_u32*)(unsigned int)(unsigned long long)l,
                                     16, 0, 0);
}

// ------------------------------------------------------------ weight cvt ----
__global__ __launch_bounds__(256) void cvt_weights(const float* __restrict__ W1,
                                                   const float* __restrict__ W2,
                                                   const float* __restrict__ W3,
                                                   ushort* __restrict__ W1b,
                                                   ushort* __restrict__ W2b,
                                                   ushort* __restrict__ W3b) {
    int i = blockIdx.x * 256 + threadIdx.x;   // float4 index, total 575488 exact
    const float4* s; ushort* d; int off;
    if (i < 49152) { s = (const float4*)W1; d = W1b; off = i; }
    else if (i < 49152 + 524288) { s = (const float4*)W2; d = W2b; off = i - 49152; }
    else { s = (const float4*)W3; d = W3b; off = i - 573440; }
    float4 v = s[off];
    ushort4 r; r.x = f2bf(v.x); r.y = f2bf(v.y); r.z = f2bf(v.z); r.w = f2bf(v.w);
    ((ushort4*)d)[off] = r;
}

// ---------------------------------------------------------------- LSTM ----
struct LstmW {
    const float* wih[4];
    const float* whh[4];
    const float* bih[4];
    const float* bhh[4];
};

__device__ __forceinline__ void gates8(const float wx[4][8], const float xv8[8],
                                       float& a0, float& a1, float& a2, float& a3) {
#pragma unroll
    for (int k = 0; k < 8; ++k) {
        float xv = xv8[k];
        a0 += wx[0][k] * xv; a1 += wx[1][k] * xv;
        a2 += wx[2][k] * xv; a3 += wx[3][k] * xv;
    }
}
__device__ __forceinline__ void cellup(float a0, float a1, float a2, float a3,
                                       float& h, float& c) {
    c = sigm(a1) * c + sigm(a0) * tanh_(a2);
    h = sigm(a3) * tanh_(c);
}
__device__ __forceinline__ void ld8(const float* p, float v[8]) {
    float4 a = *(const float4*)p;
    float4 b = *(const float4*)(p + 4);
    v[0] = a.x; v[1] = a.y; v[2] = a.z; v[3] = a.w;
    v[4] = b.x; v[5] = b.y; v[6] = b.z; v[7] = b.w;
}

__global__ __launch_bounds__(256) void lstm_kernel(const float* __restrict__ x, LstmW p,
                                                   ushort* __restrict__ Y) {
    __shared__ float xs[32 * 168];   // 32 elems x 168 inputs
    __shared__ float hb[32 * 200];   // per-elem 24*8 floats, stride 200

    const int tid = threadIdx.x;
    const int e0 = blockIdx.x * 32;
    {
        const float4* s = (const float4*)(x + (size_t)e0 * 168);
        float4* d = (float4*)xs;
        for (int i = tid; i < 1344; i += 256) d[i] = s[i];
    }
    __syncthreads();

    const int el = tid >> 3, j = tid & 7;
    float* hr = hb + el * 200;
    const float* xr = xs + el * 168;

    float wx[4][8], wh[4][8], bs4[4];

    // ---- layer 0 (in = 7, from xs) ----
    {
        const float* Wih = p.wih[0];
        const float* Whh = p.whh[0];
#pragma unroll
        for (int g = 0; g < 4; ++g) {
#pragma unroll
            for (int k = 0; k < 7; ++k) wx[g][k] = Wih[(g * 8 + j) * 7 + k];
#pragma unroll
            for (int k = 0; k < 8; ++k) wh[g][k] = Whh[(g * 8 + j) * 8 + k];
            bs4[g] = p.bih[0][g * 8 + j] + p.bhh[0][g * 8 + j];
        }
        float h = 0.f, c = 0.f;
        {
            float a0 = bs4[0], a1 = bs4[1], a2 = bs4[2], a3 = bs4[3];
#pragma unroll
            for (int k = 0; k < 7; ++k) {
                float xv = xr[k];
                a0 += wx[0][k] * xv; a1 += wx[1][k] * xv;
                a2 += wx[2][k] * xv; a3 += wx[3][k] * xv;
            }
            cellup(a0, a1, a2, a3, h, c);
            hr[j] = h;
        }
        for (int t = 1; t < 24; ++t) {
            float a0 = bs4[0], a1 = bs4[1], a2 = bs4[2], a3 = bs4[3];
#pragma unroll
            for (int k = 0; k < 7; ++k) {
                float xv = xr[t * 7 + k];
                a0 += wx[0][k] * xv; a1 += wx[1][k] * xv;
                a2 += wx[2][k] * xv; a3 += wx[3][k] * xv;
            }
            float hp[8]; ld8(&hr[(t - 1) * 8], hp);
            gates8(wh, hp, a0, a1, a2, a3);
            cellup(a0, a1, a2, a3, h, c);
            hr[t * 8 + j] = h;
        }
    }

    // ---- layers 1..3 ----
#pragma unroll
    for (int l = 1; l < 4; ++l) {
        const float* Wih = p.wih[l];
        const float* Whh = p.whh[l];
#pragma unroll
        for (int g = 0; g < 4; ++g) {
#pragma unroll
            for (int k = 0; k < 8; ++k) {
                wx[g][k] = Wih[(g * 8 + j) * 8 + k];
                wh[g][k] = Whh[(g * 8 + j) * 8 + k];
            }
            bs4[g] = p.bih[l][g * 8 + j] + p.bhh[l][g * 8 + j];
        }
        float h = 0.f, c = 0.f;
        {
            float xin[8]; ld8(&hr[0], xin);
            float a0 = bs4[0], a1 = bs4[1], a2 = bs4[2], a3 = bs4[3];
            gates8(wx, xin, a0, a1, a2, a3);
            cellup(a0, a1, a2, a3, h, c);
            hr[j] = h;
            if (l == 3) Y[((size_t)(e0 + el) * 24) * 8 + j] = f2bf(h);
        }
        for (int t = 1; t < 24; ++t) {
            float xin[8]; ld8(&hr[t * 8], xin);          // layer l-1, time t
            float hp[8];  ld8(&hr[(t - 1) * 8], hp);     // layer l,   time t-1
            float a0 = bs4[0], a1 = bs4[1], a2 = bs4[2], a3 = bs4[3];
            gates8(wx, xin, a0, a1, a2, a3);
            gates8(wh, hp, a0, a1, a2, a3);
            cellup(a0, a1, a2, a3, h, c);
            hr[t * 8 + j] = h;
            if (l == 3) Y[((size_t)(e0 + el) * 24 + t) * 8 + j] = f2bf(h);
        }
    }
}

// ---------------------------------------------------------------- GEMM ----
// Tile 256x128, BK=32; 4 waves, wave tile 128x64 (8x4 MFMA 16x16x32).
// Staging: thread tid -> row tid/4 (+i*64), 16B chunk tid%4; LDS [row][32] bf16.
template <int KDIM, bool FUSE3>
__global__ __launch_bounds__(256) void gemm_kernel(const ushort* __restrict__ A,
                                                   const ushort* __restrict__ W,
                                                   const float* __restrict__ bias,
                                                   ushort* __restrict__ Hout,
                                                   const float* __restrict__ W3,
                                                   float* __restrict__ outf, int N) {
    __shared__ ushort smem[20480];    // As [256][32] + Ws [128][32] = 40960 B
    __shared__ float w3s[FUSE3 ? 512 : 1];
    ushort* As = smem;
    ushort* Ws = smem + 8192;

    const int tid = threadIdx.x;
    const int m0 = blockIdx.x * 256;
    const int n0 = blockIdx.y * 128;
    const int lane = tid & 63;
    const int wv = tid >> 6;
    const int wm = (wv & 1) * 128;
    const int wn = (wv >> 1) * 64;
    const int m16 = lane & 15;
    const int quad = lane >> 4;

    if (FUSE3) {
        for (int i = tid; i < 512; i += 256)
            w3s[i] = W3[(size_t)(i >> 7) * 2048 + n0 + (i & 127)];
    }

    f32x4 acc[8][4];
    const f32x4 zero = {0.f, 0.f, 0.f, 0.f};
#pragma unroll
    for (int mi = 0; mi < 8; ++mi)
#pragma unroll
        for (int ni = 0; ni < 4; ++ni) acc[mi][ni] = zero;

    const int srow = tid >> 2;                 // 0..63
    const int schunk = (tid & 3) * 8;          // ushort offset
    const ushort* Ag = A + (size_t)(m0 + srow) * KDIM + schunk;
    const ushort* Wg = W + (size_t)(n0 + srow) * KDIM + schunk;
    ushort* Ald = As + wv * 512;
    ushort* Wld = Ws + wv * 512;

    for (int k0 = 0; k0 < KDIM; k0 += 32) {
#pragma unroll
        for (int i = 0; i < 4; ++i)
            g2l16(Ag + (size_t)i * 64 * KDIM + k0, Ald + i * 2048);
#pragma unroll
        for (int i = 0; i < 2; ++i)
            g2l16(Wg + (size_t)i * 64 * KDIM + k0, Wld + i * 2048);
        __syncthreads();

        bf16x8 bfr[4];
#pragma unroll
        for (int ni = 0; ni < 4; ++ni)
            bfr[ni] = *(const bf16x8*)&Ws[(wn + ni * 16 + m16) * 32 + quad * 8];
#pragma unroll
        for (int mi = 0; mi < 8; ++mi) {
            bf16x8 afr = *(const bf16x8*)&As[(wm + mi * 16 + m16) * 32 + quad * 8];
#pragma unroll
            for (int ni = 0; ni < 4; ++ni)
                acc[mi][ni] = __builtin_amdgcn_mfma_f32_16x16x32_bf16(afr, bfr[ni],
                                                                     acc[mi][ni], 0, 0, 0);
        }
        __syncthreads();
    }

    if (!FUSE3) {
#pragma unroll
        for (int ni = 0; ni < 4; ++ni) {
            const int col = n0 + wn + ni * 16 + m16;
            const float b = bias[col];
#pragma unroll
            for (int mi = 0; mi < 8; ++mi)
#pragma unroll
                for (int r = 0; r < 4; ++r) {
                    const int row = m0 + wm + mi * 16 + quad * 4 + r;
                    Hout[(size_t)row * N + col] = f2bf(fmaxf(acc[mi][ni][r] + b, 0.f));
                }
        }
    } else {
        // Two passes over 128-row halves; Cs stride 152 ushorts (304 B):
        // row-major writes 2-way-conflict-free, column dot conflict-free.
        ushort* Cs = smem;
#pragma unroll
        for (int pass = 0; pass < 2; ++pass) {
            if ((wv & 1) == pass) {
#pragma unroll
                for (int ni = 0; ni < 4; ++ni) {
                    const int cl = wn + ni * 16 + m16;
                    const float b = bias[n0 + cl];
#pragma unroll
                    for (int mi = 0; mi < 8; ++mi)
#pragma unroll
                        for (int r = 0; r < 4; ++r) {
                            const int rl = mi * 16 + quad * 4 + r;
                            Cs[rl * 152 + cl] = f2bf(fmaxf(acc[mi][ni][r] + b, 0.f));
                        }
                }
            }
            __syncthreads();
            const int r = tid & 127;
            const int na = tid >> 7;
            const ushort* crow = &Cs[r * 152];
            float p0 = 0.f, p1 = 0.f;
#pragma unroll
            for (int ch = 0; ch < 16; ++ch) {
                bf16x8 v = *(const bf16x8*)(crow + ch * 8);
#pragma unroll
                for (int q = 0; q < 8; ++q) {
                    float f = bf2f((ushort)v[q]);
                    p0 += f * w3s[na * 128 + ch * 8 + q];
                    p1 += f * w3s[(na + 2) * 128 + ch * 8 + q];
                }
            }
            atomicAdd(&outf[(size_t)(m0 + pass * 128 + r) * 4 + na], p0);
            atomicAdd(&outf[(size_t)(m0 + pass * 128 + r) * 4 + na + 2], p1);
            __syncthreads();
        }
    }
}

__global__ __launch_bounds__(256) void init_out(float* __restrict__ out,
                                                const float* __restrict__ b3) {
    const int i = blockIdx.x * 256 + threadIdx.x;
    if (i < 16384 * 4) out[i] = b3[i & 3];
}

// -------------------------------------------------------------- launch ----
extern "C" void kernel_launch(void* const* d_in, const int* in_sizes, int n_in,
                              void* d_out, int out_size, void* d_ws, size_t ws_size,
                              hipStream_t stream) {
    const float* x = (const float*)d_in[0];
    LstmW w;
    for (int l = 0; l < 4; ++l) {
        w.wih[l] = (const float*)d_in[1 + 4 * l];
        w.whh[l] = (const float*)d_in[2 + 4 * l];
        w.bih[l] = (const float*)d_in[3 + 4 * l];
        w.bhh[l] = (const float*)d_in[4 + 4 * l];
    }
    const float* Wd1 = (const float*)d_in[17];
    const float* bd1 = (const float*)d_in[18];
    const float* Wd2 = (const float*)d_in[19];
    const float* bd2 = (const float*)d_in[20];
    const float* Wd3 = (const float*)d_in[21];
    const float* bd3 = (const float*)d_in[22];
    float* out = (float*)d_out;

    ushort* Y   = (ushort*)d_ws;
    ushort* H1  = (ushort*)((char*)d_ws + 6291456);
    ushort* W1b = (ushort*)((char*)d_ws + 39845888);
    ushort* W2b = (ushort*)((char*)d_ws + 40239104);
    ushort* W3b = (ushort*)((char*)d_ws + 44433408);

    cvt_weights<<<2248, 256, 0, stream>>>(Wd1, Wd2, Wd3, W1b, W2b, W3b);
    lstm_kernel<<<512, 256, 0, stream>>>(x, w, Y);
    gemm_kernel<192, false><<<dim3(64, 8), 256, 0, stream>>>(Y, W1b, bd1, H1, nullptr, nullptr, 1024);
    init_out<<<256, 256, 0, stream>>>(out, bd3);
    gemm_kernel<1024, true><<<dim3(64, 16), 256, 0, stream>>>(H1, W2b, bd2, nullptr, Wd3, out, 2048);
}

// Round 4
// 245.145 us; speedup vs baseline: 1.3623x; 1.3623x over previous
//
#include <hip/hip_runtime.h>
#include <hip/hip_bf16.h>

// LSTM_80960133529703: B=16384, T=24, F=7, H=8, L=4; dense 192->1024->2048->4.
// R4: revert to R2's 128x128/4-wave GEMM (R3's 256-tile killed occupancy);
// add (a) BK=64 -> half the barriers, (b) XOR chunk swizzle -> conflict-free
// frag reads, (c) fuse cvt_weights + out-bias-init into the LSTM launch (5->3
// kernels). ws: Y @0 | H1 @6291456 | W1b @39845888 | W2b @40239104
typedef __attribute__((ext_vector_type(4))) float f32x4;
typedef __attribute__((ext_vector_type(8))) short bf16x8;

__device__ __forceinline__ ushort f2bf(float f) {
    union { float f; uint u; } v; v.f = f;
    uint u = v.u;
    return (ushort)((u + 0x7fffu + ((u >> 16) & 1u)) >> 16);   // RNE
}
__device__ __forceinline__ float bf2f(ushort h) {
    union { uint u; float f; } v; v.u = ((uint)h) << 16;
    return v.f;
}
__device__ __forceinline__ float sigm(float x) {
    return __builtin_amdgcn_rcpf(1.0f + __builtin_amdgcn_exp2f(x * -1.442695040888963f));
}
__device__ __forceinline__ float tanh_(float x) {
    return 2.0f * __builtin_amdgcn_rcpf(1.0f + __builtin_amdgcn_exp2f(x * -2.885390081777927f)) - 1.0f;
}

typedef const __attribute__((address_space(1))) unsigned int ga_u32;
typedef __attribute__((address_space(3))) unsigned int lds_u32;
__device__ __forceinline__ void g2l16(const void* g, void* l) {
    __builtin_amdgcn_global_load_lds((ga_u32*)(unsigned long long)g,
                                     (lds_u32*)(unsigned int)(unsigned long long)l,
                                     16, 0, 0);
}

// ---------------------------------------------------------------- LSTM ----
struct LstmW {
    const float* wih[4];
    const float* whh[4];
    const float* bih[4];
    const float* bhh[4];
};

__device__ __forceinline__ void gates8(const float wx[4][8], const float xv8[8],
                                       float& a0, float& a1, float& a2, float& a3) {
#pragma unroll
    for (int k = 0; k < 8; ++k) {
        float xv = xv8[k];
        a0 += wx[0][k] * xv; a1 += wx[1][k] * xv;
        a2 += wx[2][k] * xv; a3 += wx[3][k] * xv;
    }
}
__device__ __forceinline__ void cellup(float a0, float a1, float a2, float a3,
                                       float& h, float& c) {
    c = sigm(a1) * c + sigm(a0) * tanh_(a2);
    h = sigm(a3) * tanh_(c);
}
__device__ __forceinline__ void ld8(const float* p, float v[8]) {
    float4 a = *(const float4*)p;
    float4 b = *(const float4*)(p + 4);
    v[0] = a.x; v[1] = a.y; v[2] = a.z; v[3] = a.w;
    v[4] = b.x; v[5] = b.y; v[6] = b.z; v[7] = b.w;
}

// blocks [0,512): LSTM; blocks [512, 512+560): weight cvt fp32->bf16 (+ out init)
__global__ __launch_bounds__(256) void pre_kernel(const float* __restrict__ x, LstmW p,
                                                  ushort* __restrict__ Y,
                                                  const float* __restrict__ W1,
                                                  const float* __restrict__ W2,
                                                  ushort* __restrict__ W1b,
                                                  ushort* __restrict__ W2b,
                                                  const float* __restrict__ b3,
                                                  float* __restrict__ out) {
    __shared__ float xs[32 * 168];
    __shared__ float hb[32 * 200];

    const int tid = threadIdx.x;
    if (blockIdx.x >= 512) {
        // ---- cvt path: 560 blocks x 256 threads x 4 float4 = 573440 f4 ----
        const int tg = (blockIdx.x - 512) * 256 + tid;
        if (tg < 16384) {
            float4 bv = {b3[0], b3[1], b3[2], b3[3]};
            ((float4*)out)[tg] = bv;
        }
#pragma unroll
        for (int s = 0; s < 4; ++s) {
            int i = tg + s * 143360;
            const float4* src; ushort4* dst; int off;
            if (i < 49152) { src = (const float4*)W1; dst = (ushort4*)W1b; off = i; }
            else { src = (const float4*)W2; dst = (ushort4*)W2b; off = i - 49152; }
            float4 v = src[off];
            ushort4 r; r.x = f2bf(v.x); r.y = f2bf(v.y); r.z = f2bf(v.z); r.w = f2bf(v.w);
            dst[off] = r;
        }
        return;
    }

    const int e0 = blockIdx.x * 32;
    {
        const float4* s = (const float4*)(x + (size_t)e0 * 168);
        float4* d = (float4*)xs;
        for (int i = tid; i < 1344; i += 256) d[i] = s[i];
    }
    __syncthreads();

    const int el = tid >> 3, j = tid & 7;
    float* hr = hb + el * 200;
    const float* xr = xs + el * 168;

    float wx[4][8], wh[4][8], bs4[4];

    // ---- layer 0 (in = 7) ----
    {
        const float* Wih = p.wih[0];
        const float* Whh = p.whh[0];
#pragma unroll
        for (int g = 0; g < 4; ++g) {
#pragma unroll
            for (int k = 0; k < 7; ++k) wx[g][k] = Wih[(g * 8 + j) * 7 + k];
#pragma unroll
            for (int k = 0; k < 8; ++k) wh[g][k] = Whh[(g * 8 + j) * 8 + k];
            bs4[g] = p.bih[0][g * 8 + j] + p.bhh[0][g * 8 + j];
        }
        float h = 0.f, c = 0.f;
        {
            float a0 = bs4[0], a1 = bs4[1], a2 = bs4[2], a3 = bs4[3];
#pragma unroll
            for (int k = 0; k < 7; ++k) {
                float xv = xr[k];
                a0 += wx[0][k] * xv; a1 += wx[1][k] * xv;
                a2 += wx[2][k] * xv; a3 += wx[3][k] * xv;
            }
            cellup(a0, a1, a2, a3, h, c);
            hr[j] = h;
        }
        for (int t = 1; t < 24; ++t) {
            float a0 = bs4[0], a1 = bs4[1], a2 = bs4[2], a3 = bs4[3];
#pragma unroll
            for (int k = 0; k < 7; ++k) {
                float xv = xr[t * 7 + k];
                a0 += wx[0][k] * xv; a1 += wx[1][k] * xv;
                a2 += wx[2][k] * xv; a3 += wx[3][k] * xv;
            }
            float hp[8]; ld8(&hr[(t - 1) * 8], hp);
            gates8(wh, hp, a0, a1, a2, a3);
            cellup(a0, a1, a2, a3, h, c);
            hr[t * 8 + j] = h;
        }
    }

    // ---- layers 1..3 ----
#pragma unroll
    for (int l = 1; l < 4; ++l) {
        const float* Wih = p.wih[l];
        const float* Whh = p.whh[l];
#pragma unroll
        for (int g = 0; g < 4; ++g) {
#pragma unroll
            for (int k = 0; k < 8; ++k) {
                wx[g][k] = Wih[(g * 8 + j) * 8 + k];
                wh[g][k] = Whh[(g * 8 + j) * 8 + k];
            }
            bs4[g] = p.bih[l][g * 8 + j] + p.bhh[l][g * 8 + j];
        }
        float h = 0.f, c = 0.f;
        {
            float xin[8]; ld8(&hr[0], xin);
            float a0 = bs4[0], a1 = bs4[1], a2 = bs4[2], a3 = bs4[3];
            gates8(wx, xin, a0, a1, a2, a3);
            cellup(a0, a1, a2, a3, h, c);
            hr[j] = h;
            if (l == 3) Y[((size_t)(e0 + el) * 24) * 8 + j] = f2bf(h);
        }
        for (int t = 1; t < 24; ++t) {
            float xin[8]; ld8(&hr[t * 8], xin);
            float hp[8];  ld8(&hr[(t - 1) * 8], hp);
            float a0 = bs4[0], a1 = bs4[1], a2 = bs4[2], a3 = bs4[3];
            gates8(wx, xin, a0, a1, a2, a3);
            gates8(wh, hp, a0, a1, a2, a3);
            cellup(a0, a1, a2, a3, h, c);
            hr[t * 8 + j] = h;
            if (l == 3) Y[((size_t)(e0 + el) * 24 + t) * 8 + j] = f2bf(h);
        }
    }
}

// ---------------------------------------------------------------- GEMM ----
// Tile 128x128, BK=64, 4 waves (wave tile 64x64, 4x4 MFMA 16x16x32).
// LDS [128][64] bf16 per tensor with XOR chunk swizzle: 16B chunk at
// (row, c) stored at (row, c ^ (row&7)). Staged via global_load_lds: per wave,
// call c covers 8 rows (lane>>3), source chunk (lane&7)^(lane>>3) -> the 8
// lanes of a row still read one contiguous 128B segment. Frag reads then hit
// all 8 chunk groups across 16 rows -> 2-way only (free).
template <int KDIM, bool FUSE3>
__global__ __launch_bounds__(256) void gemm_kernel(const ushort* __restrict__ A,
                                                   const ushort* __restrict__ W,
                                                   const float* __restrict__ bias,
                                                   ushort* __restrict__ Hout,
                                                   const float* __restrict__ W3,
                                                   float* __restrict__ outf, int N) {
    constexpr int SMEMN = FUSE3 ? 17408 : 16384;   // ushorts
    __shared__ ushort smem[SMEMN];
    __shared__ float w3s[FUSE3 ? 512 : 1];
    ushort* As = smem;            // [128][64] swizzled
    ushort* Ws = smem + 8192;

    const int tid = threadIdx.x;
    const int m0 = blockIdx.x * 128;
    const int n0 = blockIdx.y * 128;
    const int lane = tid & 63;
    const int wv = tid >> 6;
    const int wm = (wv & 1) * 64;
    const int wn = (wv >> 1) * 64;
    const int m16 = lane & 15;
    const int quad = lane >> 4;

    if (FUSE3) {
        for (int i = tid; i < 512; i += 256)
            w3s[i] = W3[(size_t)(i >> 7) * 2048 + n0 + (i & 127)];
    }

    f32x4 acc[4][4];
    const f32x4 zero = {0.f, 0.f, 0.f, 0.f};
#pragma unroll
    for (int mi = 0; mi < 4; ++mi)
#pragma unroll
        for (int ni = 0; ni < 4; ++ni) acc[mi][ni] = zero;

    // staging: per wave, 4 calls/tensor; call c: rows wv*32 + c*8 + (lane>>3)
    const int lrow = lane >> 3;
    const int lchunk = (lane & 7) ^ lrow;          // XOR swizzle at source
    const ushort* Ag = A + (size_t)(m0 + wv * 32 + lrow) * KDIM + lchunk * 8;
    const ushort* Wg = W + (size_t)(n0 + wv * 32 + lrow) * KDIM + lchunk * 8;
    ushort* Ald = As + wv * 2048;
    ushort* Wld = Ws + wv * 2048;

    // frag-read swizzled chunk offsets (row&7 == m16&7)
    const int r7 = m16 & 7;
    const int ck0 = (quad ^ r7) * 8;          // kk = 0
    const int ck1 = ((quad + 4) ^ r7) * 8;    // kk = 1

    for (int k0 = 0; k0 < KDIM; k0 += 64) {
#pragma unroll
        for (int c = 0; c < 4; ++c)
            g2l16(Ag + (size_t)c * 8 * KDIM + k0, Ald + c * 512);
#pragma unroll
        for (int c = 0; c < 4; ++c)
            g2l16(Wg + (size_t)c * 8 * KDIM + k0, Wld + c * 512);
        __syncthreads();

#pragma unroll
        for (int kk = 0; kk < 2; ++kk) {
            const int ck = kk ? ck1 : ck0;
            bf16x8 bfr[4];
#pragma unroll
            for (int ni = 0; ni < 4; ++ni)
                bfr[ni] = *(const bf16x8*)&Ws[(wn + ni * 16 + m16) * 64 + ck];
#pragma unroll
            for (int mi = 0; mi < 4; ++mi) {
                bf16x8 afr = *(const bf16x8*)&As[(wm + mi * 16 + m16) * 64 + ck];
#pragma unroll
                for (int ni = 0; ni < 4; ++ni)
                    acc[mi][ni] = __builtin_amdgcn_mfma_f32_16x16x32_bf16(afr, bfr[ni],
                                                                         acc[mi][ni], 0, 0, 0);
            }
        }
        __syncthreads();
    }

    if (!FUSE3) {
#pragma unroll
        for (int ni = 0; ni < 4; ++ni) {
            const int col = n0 + wn + ni * 16 + m16;
            const float b = bias[col];
#pragma unroll
            for (int mi = 0; mi < 4; ++mi)
#pragma unroll
                for (int r = 0; r < 4; ++r) {
                    const int row = m0 + wm + mi * 16 + quad * 4 + r;
                    Hout[(size_t)row * N + col] = f2bf(fmaxf(acc[mi][ni][r] + b, 0.f));
                }
        }
    } else {
        ushort* Cs = smem;   // [128][136]
#pragma unroll
        for (int ni = 0; ni < 4; ++ni) {
            const int cl = wn + ni * 16 + m16;
            const float b = bias[n0 + cl];
#pragma unroll
            for (int mi = 0; mi < 4; ++mi)
#pragma unroll
                for (int r = 0; r < 4; ++r) {
                    const int rl = wm + mi * 16 + quad * 4 + r;
                    Cs[rl * 136 + cl] = f2bf(fmaxf(acc[mi][ni][r] + b, 0.f));
                }
        }
        __syncthreads();
        const int r = tid & 127;
        const int na = tid >> 7;
        const ushort* crow = &Cs[r * 136];
        float p0 = 0.f, p1 = 0.f;
#pragma unroll
        for (int ch = 0; ch < 16; ++ch) {
            bf16x8 v = *(const bf16x8*)(crow + ch * 8);
#pragma unroll
            for (int q = 0; q < 8; ++q) {
                float f = bf2f((ushort)v[q]);
                p0 += f * w3s[na * 128 + ch * 8 + q];
                p1 += f * w3s[(na + 2) * 128 + ch * 8 + q];
            }
        }
        atomicAdd(&outf[(size_t)(m0 + r) * 4 + na], p0);
        atomicAdd(&outf[(size_t)(m0 + r) * 4 + na + 2], p1);
    }
}

// -------------------------------------------------------------- launch ----
extern "C" void kernel_launch(void* const* d_in, const int* in_sizes, int n_in,
                              void* d_out, int out_size, void* d_ws, size_t ws_size,
                              hipStream_t stream) {
    const float* x = (const float*)d_in[0];
    LstmW w;
    for (int l = 0; l < 4; ++l) {
        w.wih[l] = (const float*)d_in[1 + 4 * l];
        w.whh[l] = (const float*)d_in[2 + 4 * l];
        w.bih[l] = (const float*)d_in[3 + 4 * l];
        w.bhh[l] = (const float*)d_in[4 + 4 * l];
    }
    const float* Wd1 = (const float*)d_in[17];
    const float* bd1 = (const float*)d_in[18];
    const float* Wd2 = (const float*)d_in[19];
    const float* bd2 = (const float*)d_in[20];
    const float* Wd3 = (const float*)d_in[21];
    const float* bd3 = (const float*)d_in[22];
    float* out = (float*)d_out;

    ushort* Y   = (ushort*)d_ws;
    ushort* H1  = (ushort*)((char*)d_ws + 6291456);
    ushort* W1b = (ushort*)((char*)d_ws + 39845888);
    ushort* W2b = (ushort*)((char*)d_ws + 40239104);

    pre_kernel<<<1072, 256, 0, stream>>>(x, w, Y, Wd1, Wd2, W1b, W2b, bd3, out);
    gemm_kernel<192, false><<<dim3(128, 8), 256, 0, stream>>>(Y, W1b, bd1, H1, nullptr, nullptr, 1024);
    gemm_kernel<1024, true><<<dim3(128, 16), 256, 0, stream>>>(H1, W2b, bd2, nullptr, Wd3, out, 2048);
}

// Round 5
// 234.975 us; speedup vs baseline: 1.4213x; 1.0433x over previous
//
#include <hip/hip_runtime.h>
#include <hip/hip_bf16.h>

// LSTM_80960133529703: B=16384, T=24, F=7, H=8, L=4; dense 192->1024->2048->4.
// R5: (a) FUSE3 epilogue -> two-pass f32 Cs (no bf16 pack/unpack, conflict-free
//     b128 dots, w3s stride 132); (b) gemm grids n-fastest for A-tile L2 reuse;
//     (c) LSTM gate math packed as float2 -> v_pk_fma_f32.
// ws: Y @0 | H1 @6291456 | W1b @39845888 | W2b @40239104
typedef __attribute__((ext_vector_type(4))) float f32x4;
typedef __attribute__((ext_vector_type(2))) float f32x2;
typedef __attribute__((ext_vector_type(8))) short bf16x8;

__device__ __forceinline__ ushort f2bf(float f) {
    union { float f; uint u; } v; v.f = f;
    uint u = v.u;
    return (ushort)((u + 0x7fffu + ((u >> 16) & 1u)) >> 16);   // RNE
}
__device__ __forceinline__ float sigm(float x) {
    return __builtin_amdgcn_rcpf(1.0f + __builtin_amdgcn_exp2f(x * -1.442695040888963f));
}
__device__ __forceinline__ float tanh_(float x) {
    return 2.0f * __builtin_amdgcn_rcpf(1.0f + __builtin_amdgcn_exp2f(x * -2.885390081777927f)) - 1.0f;
}

typedef const __attribute__((address_space(1))) unsigned int ga_u32;
typedef __attribute__((address_space(3))) unsigned int lds_u32;
__device__ __forceinline__ void g2l16(const void* g, void* l) {
    __builtin_amdgcn_global_load_lds((ga_u32*)(unsigned long long)g,
                                     (lds_u32*)(unsigned int)(unsigned long long)l,
                                     16, 0, 0);
}

// ---------------------------------------------------------------- LSTM ----
struct LstmW {
    const float* wih[4];
    const float* whh[4];
    const float* bih[4];
    const float* bhh[4];
};

__device__ __forceinline__ void gates8p(const f32x2 w01[8], const f32x2 w23[8],
                                        const float xv8[8], f32x2& a01, f32x2& a23) {
#pragma unroll
    for (int k = 0; k < 8; ++k) {
        f32x2 xv = {xv8[k], xv8[k]};
        a01 += w01[k] * xv;
        a23 += w23[k] * xv;
    }
}
__device__ __forceinline__ void cellup(f32x2 a01, f32x2 a23, float& h, float& c) {
    c = sigm(a01.y) * c + sigm(a01.x) * tanh_(a23.x);
    h = sigm(a23.y) * tanh_(c);
}
__device__ __forceinline__ void ld8(const float* p, float v[8]) {
    float4 a = *(const float4*)p;
    float4 b = *(const float4*)(p + 4);
    v[0] = a.x; v[1] = a.y; v[2] = a.z; v[3] = a.w;
    v[4] = b.x; v[5] = b.y; v[6] = b.z; v[7] = b.w;
}

// blocks [0,512): LSTM; blocks [512, 512+560): weight cvt fp32->bf16 (+ out init)
__global__ __launch_bounds__(256) void pre_kernel(const float* __restrict__ x, LstmW p,
                                                  ushort* __restrict__ Y,
                                                  const float* __restrict__ W1,
                                                  const float* __restrict__ W2,
                                                  ushort* __restrict__ W1b,
                                                  ushort* __restrict__ W2b,
                                                  const float* __restrict__ b3,
                                                  float* __restrict__ out) {
    __shared__ float xs[32 * 168];
    __shared__ float hb[32 * 200];

    const int tid = threadIdx.x;
    if (blockIdx.x >= 512) {
        // ---- cvt path: 560 blocks x 256 threads x 4 float4 = 573440 f4 ----
        const int tg = (blockIdx.x - 512) * 256 + tid;
        if (tg < 16384) {
            float4 bv = {b3[0], b3[1], b3[2], b3[3]};
            ((float4*)out)[tg] = bv;
        }
#pragma unroll
        for (int s = 0; s < 4; ++s) {
            int i = tg + s * 143360;
            const float4* src; ushort4* dst; int off;
            if (i < 49152) { src = (const float4*)W1; dst = (ushort4*)W1b; off = i; }
            else { src = (const float4*)W2; dst = (ushort4*)W2b; off = i - 49152; }
            float4 v = src[off];
            ushort4 r; r.x = f2bf(v.x); r.y = f2bf(v.y); r.z = f2bf(v.z); r.w = f2bf(v.w);
            dst[off] = r;
        }
        return;
    }

    const int e0 = blockIdx.x * 32;
    {
        const float4* s = (const float4*)(x + (size_t)e0 * 168);
        float4* d = (float4*)xs;
        for (int i = tid; i < 1344; i += 256) d[i] = s[i];
    }
    __syncthreads();

    const int el = tid >> 3, j = tid & 7;
    float* hr = hb + el * 200;
    const float* xr = xs + el * 168;

    f32x2 wx01[8], wx23[8], wh01[8], wh23[8], b01, b23;

    // ---- layer 0 (in = 7) ----
    {
        const float* Wih = p.wih[0];
        const float* Whh = p.whh[0];
#pragma unroll
        for (int k = 0; k < 7; ++k) {
            wx01[k] = {Wih[(0 + j) * 7 + k], Wih[(8 + j) * 7 + k]};
            wx23[k] = {Wih[(16 + j) * 7 + k], Wih[(24 + j) * 7 + k]};
        }
#pragma unroll
        for (int k = 0; k < 8; ++k) {
            wh01[k] = {Whh[(0 + j) * 8 + k], Whh[(8 + j) * 8 + k]};
            wh23[k] = {Whh[(16 + j) * 8 + k], Whh[(24 + j) * 8 + k]};
        }
        b01 = {p.bih[0][j] + p.bhh[0][j], p.bih[0][8 + j] + p.bhh[0][8 + j]};
        b23 = {p.bih[0][16 + j] + p.bhh[0][16 + j], p.bih[0][24 + j] + p.bhh[0][24 + j]};

        float h = 0.f, c = 0.f;
        {
            f32x2 a01 = b01, a23 = b23;
#pragma unroll
            for (int k = 0; k < 7; ++k) {
                f32x2 xv = {xr[k], xr[k]};
                a01 += wx01[k] * xv; a23 += wx23[k] * xv;
            }
            cellup(a01, a23, h, c);
            hr[j] = h;
        }
        for (int t = 1; t < 24; ++t) {
            f32x2 a01 = b01, a23 = b23;
#pragma unroll
            for (int k = 0; k < 7; ++k) {
                f32x2 xv = {xr[t * 7 + k], xr[t * 7 + k]};
                a01 += wx01[k] * xv; a23 += wx23[k] * xv;
            }
            float hp[8]; ld8(&hr[(t - 1) * 8], hp);
            gates8p(wh01, wh23, hp, a01, a23);
            cellup(a01, a23, h, c);
            hr[t * 8 + j] = h;
        }
    }

    // ---- layers 1..3 ----
#pragma unroll
    for (int l = 1; l < 4; ++l) {
        const float* Wih = p.wih[l];
        const float* Whh = p.whh[l];
#pragma unroll
        for (int k = 0; k < 8; ++k) {
            wx01[k] = {Wih[(0 + j) * 8 + k], Wih[(8 + j) * 8 + k]};
            wx23[k] = {Wih[(16 + j) * 8 + k], Wih[(24 + j) * 8 + k]};
            wh01[k] = {Whh[(0 + j) * 8 + k], Whh[(8 + j) * 8 + k]};
            wh23[k] = {Whh[(16 + j) * 8 + k], Whh[(24 + j) * 8 + k]};
        }
        b01 = {p.bih[l][j] + p.bhh[l][j], p.bih[l][8 + j] + p.bhh[l][8 + j]};
        b23 = {p.bih[l][16 + j] + p.bhh[l][16 + j], p.bih[l][24 + j] + p.bhh[l][24 + j]};

        float h = 0.f, c = 0.f;
        {
            float xin[8]; ld8(&hr[0], xin);
            f32x2 a01 = b01, a23 = b23;
            gates8p(wx01, wx23, xin, a01, a23);
            cellup(a01, a23, h, c);
            hr[j] = h;
            if (l == 3) Y[((size_t)(e0 + el) * 24) * 8 + j] = f2bf(h);
        }
        for (int t = 1; t < 24; ++t) {
            float xin[8]; ld8(&hr[t * 8], xin);
            float hp[8];  ld8(&hr[(t - 1) * 8], hp);
            f32x2 a01 = b01, a23 = b23;
            gates8p(wx01, wx23, xin, a01, a23);
            gates8p(wh01, wh23, hp, a01, a23);
            cellup(a01, a23, h, c);
            hr[t * 8 + j] = h;
            if (l == 3) Y[((size_t)(e0 + el) * 24 + t) * 8 + j] = f2bf(h);
        }
    }
}

// ---------------------------------------------------------------- GEMM ----
// Tile 128x128, BK=64, 4 waves (wave tile 64x64, 4x4 MFMA 16x16x32).
// Grid: blockIdx.x = n (fastest -> consecutive blocks share A-tile),
// blockIdx.y = m. LDS [128][64] bf16 XOR-chunk-swizzled (R4, conflict-free).
// FUSE3 epilogue: two-pass f32 Cs[64][132] + w3s[4][132], b128 dots, atomics.
template <int KDIM, bool FUSE3>
__global__ __launch_bounds__(256) void gemm_kernel(const ushort* __restrict__ A,
                                                   const ushort* __restrict__ W,
                                                   const float* __restrict__ bias,
                                                   ushort* __restrict__ Hout,
                                                   const float* __restrict__ W3,
                                                   float* __restrict__ outf, int N) {
    constexpr int SMEMN = FUSE3 ? 17408 : 16384;   // ushorts; FUSE3: Cs 64x132 f32
    __shared__ alignas(16) ushort smem[SMEMN];
    __shared__ alignas(16) float w3s[FUSE3 ? 528 : 1];
    ushort* As = smem;            // [128][64] swizzled
    ushort* Ws = smem + 8192;

    const int tid = threadIdx.x;
    const int n0 = blockIdx.x * 128;
    const int m0 = blockIdx.y * 128;
    const int lane = tid & 63;
    const int wv = tid >> 6;
    const int wm = (wv & 1) * 64;
    const int wn = (wv >> 1) * 64;
    const int m16 = lane & 15;
    const int quad = lane >> 4;

    if (FUSE3) {
        for (int i = tid; i < 512; i += 256)
            w3s[(i >> 7) * 132 + (i & 127)] = W3[(size_t)(i >> 7) * 2048 + n0 + (i & 127)];
    }

    f32x4 acc[4][4];
    const f32x4 zero = {0.f, 0.f, 0.f, 0.f};
#pragma unroll
    for (int mi = 0; mi < 4; ++mi)
#pragma unroll
        for (int ni = 0; ni < 4; ++ni) acc[mi][ni] = zero;

    // staging: per wave, 4 calls/tensor; call c: rows wv*32 + c*8 + (lane>>3)
    const int lrow = lane >> 3;
    const int lchunk = (lane & 7) ^ lrow;          // XOR swizzle at source
    const ushort* Ag = A + (size_t)(m0 + wv * 32 + lrow) * KDIM + lchunk * 8;
    const ushort* Wg = W + (size_t)(n0 + wv * 32 + lrow) * KDIM + lchunk * 8;
    ushort* Ald = As + wv * 2048;
    ushort* Wld = Ws + wv * 2048;

    // frag-read swizzled chunk offsets (row&7 == m16&7)
    const int r7 = m16 & 7;
    const int ck0 = (quad ^ r7) * 8;          // kk = 0
    const int ck1 = ((quad + 4) ^ r7) * 8;    // kk = 1

    for (int k0 = 0; k0 < KDIM; k0 += 64) {
#pragma unroll
        for (int c = 0; c < 4; ++c)
            g2l16(Ag + (size_t)c * 8 * KDIM + k0, Ald + c * 512);
#pragma unroll
        for (int c = 0; c < 4; ++c)
            g2l16(Wg + (size_t)c * 8 * KDIM + k0, Wld + c * 512);
        __syncthreads();

#pragma unroll
        for (int kk = 0; kk < 2; ++kk) {
            const int ck = kk ? ck1 : ck0;
            bf16x8 bfr[4];
#pragma unroll
            for (int ni = 0; ni < 4; ++ni)
                bfr[ni] = *(const bf16x8*)&Ws[(wn + ni * 16 + m16) * 64 + ck];
#pragma unroll
            for (int mi = 0; mi < 4; ++mi) {
                bf16x8 afr = *(const bf16x8*)&As[(wm + mi * 16 + m16) * 64 + ck];
#pragma unroll
                for (int ni = 0; ni < 4; ++ni)
                    acc[mi][ni] = __builtin_amdgcn_mfma_f32_16x16x32_bf16(afr, bfr[ni],
                                                                         acc[mi][ni], 0, 0, 0);
            }
        }
        __syncthreads();
    }

    if (!FUSE3) {
#pragma unroll
        for (int ni = 0; ni < 4; ++ni) {
            const int col = n0 + wn + ni * 16 + m16;
            const float b = bias[col];
#pragma unroll
            for (int mi = 0; mi < 4; ++mi)
#pragma unroll
                for (int r = 0; r < 4; ++r) {
                    const int row = m0 + wm + mi * 16 + quad * 4 + r;
                    Hout[(size_t)row * N + col] = f2bf(fmaxf(acc[mi][ni][r] + b, 0.f));
                }
        }
    } else {
        // Two passes over 64-row halves; Cs [64][132] f32 (33792 B overlays smem).
        // Writes: 16 consecutive banks per (quad) group, 2-way max. Dots: thread
        // (row=tid>>2, n=tid&3): Cs broadcast x 2-way, w3s stride 132 -> distinct
        // banks per n, broadcast within n. All free per m136.
        float* Cs = (float*)smem;
        const int drow = tid >> 2;
        const int dn = tid & 3;
#pragma unroll
        for (int pass = 0; pass < 2; ++pass) {
            if ((wv & 1) == pass) {
#pragma unroll
                for (int ni = 0; ni < 4; ++ni) {
                    const int cl = wn + ni * 16 + m16;
                    const float b = bias[n0 + cl];
#pragma unroll
                    for (int mi = 0; mi < 4; ++mi)
#pragma unroll
                        for (int r = 0; r < 4; ++r) {
                            const int rl = mi * 16 + quad * 4 + r;   // 0..63
                            Cs[rl * 132 + cl] = fmaxf(acc[mi][ni][r] + b, 0.f);
                        }
                }
            }
            __syncthreads();
            const float* crow = &Cs[drow * 132];
            const float* wrow = &w3s[dn * 132];
            float p = 0.f;
#pragma unroll
            for (int ch = 0; ch < 32; ++ch) {
                f32x4 cv = *(const f32x4*)(crow + ch * 4);
                f32x4 wv4 = *(const f32x4*)(wrow + ch * 4);
                p += cv[0] * wv4[0] + cv[1] * wv4[1] + cv[2] * wv4[2] + cv[3] * wv4[3];
            }
            atomicAdd(&outf[(size_t)(m0 + pass * 64 + drow) * 4 + dn], p);
            __syncthreads();
        }
    }
}

// -------------------------------------------------------------- launch ----
extern "C" void kernel_launch(void* const* d_in, const int* in_sizes, int n_in,
                              void* d_out, int out_size, void* d_ws, size_t ws_size,
                              hipStream_t stream) {
    const float* x = (const float*)d_in[0];
    LstmW w;
    for (int l = 0; l < 4; ++l) {
        w.wih[l] = (const float*)d_in[1 + 4 * l];
        w.whh[l] = (const float*)d_in[2 + 4 * l];
        w.bih[l] = (const float*)d_in[3 + 4 * l];
        w.bhh[l] = (const float*)d_in[4 + 4 * l];
    }
    const float* Wd1 = (const float*)d_in[17];
    const float* bd1 = (const float*)d_in[18];
    const float* Wd2 = (const float*)d_in[19];
    const float* bd2 = (const float*)d_in[20];
    const float* Wd3 = (const float*)d_in[21];
    const float* bd3 = (const float*)d_in[22];
    float* out = (float*)d_out;

    ushort* Y   = (ushort*)d_ws;
    ushort* H1  = (ushort*)((char*)d_ws + 6291456);
    ushort* W1b = (ushort*)((char*)d_ws + 39845888);
    ushort* W2b = (ushort*)((char*)d_ws + 40239104);

    pre_kernel<<<1072, 256, 0, stream>>>(x, w, Y, Wd1, Wd2, W1b, W2b, bd3, out);
    gemm_kernel<192, false><<<dim3(8, 128), 256, 0, stream>>>(Y, W1b, bd1, H1, nullptr, nullptr, 1024);
    gemm_kernel<1024, true><<<dim3(16, 128), 256, 0, stream>>>(H1, W2b, bd2, nullptr, Wd3, out, 2048);
}